// Round 13
// baseline (200.360 us; speedup 1.0000x reference)
//
#include <hip/hip_runtime.h>
#include <hip/hip_bf16.h>

// RedistributionNetwork: 128 sequential tridiagonal layers on [256,1024] f32 state.
// Single fused kernel: blocks 0..127 gather 4-layer tridiags (one dwordx4/row)
// and compose depth-4 products -> bf16 band9[32][9][1024]; blocks 128..383 run
// the 32-step 9-diagonal propagation (R11 structure), consuming quads as they
// are published via device-scope packed flags (producer-consumer overlap).
// Deadlock-free: __launch_bounds__(512,4) => >=2 blocks/CU => all 384 blocks
// co-resident regardless of dispatch order.

#define NXL 128
#define NYP 1024
#define NB  256
#define NQ  32     // quads (4 layers each)
#define NGB 128    // gather blocks (4 per quad)
#define SL2 256    // composed rows per gather block
#define HR2 272    // staged rows per layer per gather block (SL2 + 8 each side)

struct __attribute__((packed, aligned(4))) f4u { float x, y, z, w; };

__global__ __launch_bounds__(64) void init_flags(unsigned long long* flags64) {
    if (threadIdx.x < 4) flags64[threadIdx.x] = 0ull;
}

// ---------------- propagate machinery (identical math to round 11) ----------------
__device__ __forceinline__ float blo(unsigned u) { return __uint_as_float(u << 16); }
__device__ __forceinline__ float bhi(unsigned u) { return __uint_as_float(u & 0xffff0000u); }

__device__ __forceinline__ void ldsbar() {
    asm volatile("s_waitcnt lgkmcnt(0)" ::: "memory");
    __builtin_amdgcn_s_barrier();
}

__device__ __forceinline__ void loadW(const __hip_bfloat16* __restrict__ band9,
                                      int q, int R, unsigned (&u)[9]) {
    const __hip_bfloat16* base = band9 + (size_t)q * 9 * NYP + R;
#pragma unroll
    for (int d = 0; d < 9; ++d)
        u[d] = *reinterpret_cast<const unsigned*>(base + d * NYP);
}

__device__ __forceinline__ void read_halo(const float (*cur)[2][4], int w,
                                          float (&hL)[4], float (&hR)[4]) {
#pragma unroll
    for (int j = 0; j < 4; ++j) {
        hL[j] = (w > 0) ? cur[w - 1][1][j] : 0.0f;
        hR[j] = (w < 7) ? cur[w + 1][0][j] : 0.0f;
    }
}

__device__ __forceinline__ void stepX(float& h0, float& h1, const unsigned (&q)[9],
                                      float (&hL)[4], float (&hR)[4],
                                      float (*nxt)[2][4], int w, int l) {
    float lh0 = __shfl_up(h0, 2),   lh1 = __shfl_up(h1, 2);
    float lh2 = __shfl_up(h0, 1),   lh3 = __shfl_up(h1, 1);
    float rh0 = __shfl_down(h0, 1), rh1 = __shfl_down(h1, 1);
    float rh2 = __shfl_down(h0, 2), rh3 = __shfl_down(h1, 2);
    if (l == 0)  { lh0 = hL[0]; lh1 = hL[1]; lh2 = hL[2]; lh3 = hL[3]; }
    if (l == 1)  { lh0 = hL[2]; lh1 = hL[3]; }
    if (l == 63) { rh0 = hR[0]; rh1 = hR[1]; rh2 = hR[2]; rh3 = hR[3]; }
    if (l == 62) { rh2 = hR[0]; rh3 = hR[1]; }

    float n0 =            blo(q[0]) * lh0;
    n0 = fmaf(blo(q[1]), lh1, n0);
    n0 = fmaf(blo(q[2]), lh2, n0);
    n0 = fmaf(blo(q[3]), lh3, n0);
    n0 = fmaf(blo(q[4]), h0,  n0);
    n0 = fmaf(blo(q[5]), h1,  n0);
    n0 = fmaf(blo(q[6]), rh0, n0);
    n0 = fmaf(blo(q[7]), rh1, n0);
    n0 = fmaf(blo(q[8]), rh2, n0);
    float n1 =            bhi(q[0]) * lh1;
    n1 = fmaf(bhi(q[1]), lh2, n1);
    n1 = fmaf(bhi(q[2]), lh3, n1);
    n1 = fmaf(bhi(q[3]), h0,  n1);
    n1 = fmaf(bhi(q[4]), h1,  n1);
    n1 = fmaf(bhi(q[5]), rh0, n1);
    n1 = fmaf(bhi(q[6]), rh1, n1);
    n1 = fmaf(bhi(q[7]), rh2, n1);
    n1 = fmaf(bhi(q[8]), rh3, n1);
    h0 = n0; h1 = n1;

    if (l < 2)   { nxt[w][0][2 * l]        = h0; nxt[w][0][2 * l + 1]        = h1; }
    if (l >= 62) { nxt[w][1][2 * (l - 62)] = h0; nxt[w][1][2 * (l - 62) + 1] = h1; }
    ldsbar();
    read_halo(nxt, w, hL, hR);
}

// ---------------- fused kernel ----------------
__global__ __launch_bounds__(512, 4) void fused(const float* __restrict__ x,
                                                const float* __restrict__ W,
                                                __hip_bfloat16* __restrict__ band9,
                                                unsigned long long* __restrict__ flags64,
                                                float* __restrict__ out) {
    __shared__ float ta[4][3][HR2];                 // gather staging (13 KB)
    __shared__ float hal[2][8][2][4];               // propagate halo parity
    __shared__ unsigned long long fcache[4];        // consumer flag cache
    const int tid = threadIdx.x;

    if (blockIdx.x < NGB) {
        // ================= gather + compose path =================
        const int q  = blockIdx.x >> 2;
        const int sl = blockIdx.x & 3;
        const int i0 = sl * SL2;

        for (int gi = tid; gi < 4 * HR2; gi += 512) {
            int ly = gi / HR2;
            int rr = gi - ly * HR2;
            int i  = i0 - 8 + rr;
            float a = 0.0f, b = 0.0f, c = 0.0f;
            if ((unsigned)i < NYP) {
                size_t base = ((size_t)(4 * q + ly) << 20) + (size_t)i * (NYP + 1);
                const float* lp = W + base + ((i == 0) ? 0 : (i == NYP - 1) ? -3 : -1);
                f4u v = *reinterpret_cast<const f4u*>(lp);
                if (i == 0)            { a = 0.0f; b = v.x; c = v.y; }
                else if (i == NYP - 1) { a = v.z;  b = v.w; c = 0.0f; }
                else                   { a = v.x;  b = v.y; c = v.z; }
            }
            ta[ly][0][rr] = a;
            ta[ly][1][rr] = b;
            ta[ly][2][rr] = c;
        }
        __syncthreads();

        if (tid < SL2) {
            const int i  = i0 + tid;
            const int li = tid + 8;   // LDS slot of row i; col i+o -> slot li+o
            float p[11], r[11];
#pragma unroll
            for (int k = 0; k < 11; ++k) { p[k] = 0.0f; r[k] = 0.0f; }
            p[4] = ta[3][0][li]; p[5] = ta[3][1][li]; p[6] = ta[3][2][li];

#pragma unroll
            for (int d = -2; d <= 2; ++d)
                r[d + 5] = fmaf(p[d + 6], ta[2][0][li + d + 1],
                           fmaf(p[d + 5], ta[2][1][li + d],
                                p[d + 4] * ta[2][2][li + d - 1]));
#pragma unroll
            for (int k = 0; k < 11; ++k) p[k] = r[k];

#pragma unroll
            for (int d = -3; d <= 3; ++d)
                r[d + 5] = fmaf(p[d + 6], ta[1][0][li + d + 1],
                           fmaf(p[d + 5], ta[1][1][li + d],
                                p[d + 4] * ta[1][2][li + d - 1]));
#pragma unroll
            for (int k = 0; k < 11; ++k) p[k] = r[k];

#pragma unroll
            for (int d = -4; d <= 4; ++d)
                r[d + 5] = fmaf(p[d + 6], ta[0][0][li + d + 1],
                           fmaf(p[d + 5], ta[0][1][li + d],
                                p[d + 4] * ta[0][2][li + d - 1]));

            __hip_bfloat16* dst = band9 + (size_t)q * 9 * NYP + i;
#pragma unroll
            for (int d = 0; d < 9; ++d)
                dst[d * NYP] = __float2bfloat16(r[d + 1]);
        }
        __threadfence();        // make band9 writes device-visible
        __syncthreads();        // all threads' stores fenced before flag
        if (tid == 0)
            atomicAdd(&flags64[q >> 3], 1ull << (8 * (q & 7)));
    } else {
        // ================= propagate path (round-11 structure) =================
        const int b = blockIdx.x - NGB;
        const int w = tid >> 6;
        const int l = tid & 63;
        const int R = tid << 1;

        if (tid < 4) fcache[tid] = 0ull;

        float h0, h1;
        {
            float2 v = *reinterpret_cast<const float2*>(x + (size_t)b * NYP + R);
            h0 = v.x; h1 = v.y;
        }
        __syncthreads();   // fcache init visible

        // wait for quad qq to be fully published (4 slices); cached-flag fast path
        auto waitq = [&](int qq) {
            const int sel = qq >> 3, sh = 8 * (qq & 7);
            unsigned long long cv = fcache[sel];          // LDS broadcast read
            if (((cv >> sh) & 0xffull) >= 4ull) return;   // already known done
            if (tid == 0) {
                unsigned long long v;
                do {
                    v = atomicAdd(&flags64[sel], 0ull);   // device-scope read
                    if (((v >> sh) & 0xffull) >= 4ull) break;
                    __builtin_amdgcn_s_sleep(8);
                } while (true);
                fcache[sel] = v;
            }
            __syncthreads();
            __threadfence();   // acquire: newly published band9 lines
        };

        unsigned qa[9], qb[9];
        waitq(0);
        loadW(band9, 0, R, qa);

        if (l < 2)   { hal[0][w][0][2 * l]        = h0; hal[0][w][0][2 * l + 1]        = h1; }
        if (l >= 62) { hal[0][w][1][2 * (l - 62)] = h0; hal[0][w][1][2 * (l - 62) + 1] = h1; }
        ldsbar();
        float hL[4], hR[4];
        read_halo(hal[0], w, hL, hR);

#pragma unroll 1
        for (int s = 0; s < NQ; s += 2) {
            int s1 = (s + 1 < NQ) ? s + 1 : NQ - 1;
            waitq(s1);
            loadW(band9, s1, R, qb);
            stepX(h0, h1, qa, hL, hR, hal[1], w, l);
            int s2 = (s + 2 < NQ) ? s + 2 : NQ - 1;
            waitq(s2);
            loadW(band9, s2, R, qa);
            stepX(h0, h1, qb, hL, hR, hal[0], w, l);
        }

        *reinterpret_cast<float2*>(out + (size_t)b * NYP + R) = make_float2(h0, h1);
    }
}

// ---------------- fallback: direct tridiag sweep from W (ws too small) ----------------
__device__ __forceinline__ float gAw(const float* __restrict__ Wl, int r) {
    return (r >= 1 && r < NYP) ? Wl[(size_t)r * NYP + (r - 1)] : 0.0f;
}
__device__ __forceinline__ float gBw(const float* __restrict__ Wl, int r) {
    return ((unsigned)r < NYP) ? Wl[(size_t)r * NYP + r] : 0.0f;
}
__device__ __forceinline__ float gCw(const float* __restrict__ Wl, int r) {
    return (r >= 0 && r < NYP - 1) ? Wl[(size_t)r * NYP + (r + 1)] : 0.0f;
}

__global__ __launch_bounds__(64) void propagate_direct(const float* __restrict__ x,
                                                       const float* __restrict__ W,
                                                       float* __restrict__ out) {
    const int b    = blockIdx.x;
    const int lane = threadIdx.x & 63;
    const int r0   = lane * 16;

    float h[16];
    const float4* xb = reinterpret_cast<const float4*>(x + (size_t)b * NYP + r0);
#pragma unroll
    for (int t = 0; t < 4; ++t) {
        float4 v = xb[t];
        h[4 * t + 0] = v.x; h[4 * t + 1] = v.y;
        h[4 * t + 2] = v.z; h[4 * t + 3] = v.w;
    }

#pragma unroll 1
    for (int ll = 0; ll < NXL; ++ll) {
        const float* Wl = W + ((size_t)ll << 20);
        float a[16], bb[16], c[16];
#pragma unroll
        for (int k = 0; k < 16; ++k) {
            int i = r0 + k;
            a[k] = gAw(Wl, i); bb[k] = gBw(Wl, i); c[k] = gCw(Wl, i);
        }
        float left  = __shfl_up(h[15], 1);
        float right = __shfl_down(h[0], 1);
        float carry = left;
        float n[16];
#pragma unroll
        for (int j = 0; j < 16; ++j) {
            float hp = (j == 15) ? right : h[j + 1];
            n[j] = fmaf(a[j], carry, fmaf(bb[j], h[j], c[j] * hp));
            carry = h[j];
        }
#pragma unroll
        for (int j = 0; j < 16; ++j) h[j] = n[j];
    }

    float4* ob = reinterpret_cast<float4*>(out + (size_t)b * NYP + r0);
#pragma unroll
    for (int t = 0; t < 4; ++t)
        ob[t] = make_float4(h[4 * t + 0], h[4 * t + 1], h[4 * t + 2], h[4 * t + 3]);
}

extern "C" void kernel_launch(void* const* d_in, const int* in_sizes, int n_in,
                              void* d_out, int out_size, void* d_ws, size_t ws_size,
                              hipStream_t stream) {
    const float* x = (const float*)d_in[0];   // [256,1024] f32
    const float* W = (const float*)d_in[1];   // [128,1024,1024] f32
    float* out = (float*)d_out;               // [256,1024] f32

    const size_t band9Bytes = (size_t)NQ * 9 * NYP * sizeof(__hip_bfloat16);  // 576 KB
    if (ws_size >= band9Bytes + 32) {
        __hip_bfloat16* band9 = (__hip_bfloat16*)d_ws;
        unsigned long long* flags64 = (unsigned long long*)((char*)d_ws + band9Bytes);
        init_flags<<<1, 64, 0, stream>>>(flags64);          // d_ws not re-poisoned
        fused<<<NGB + NB, 512, 0, stream>>>(x, W, band9, flags64, out);
    } else {
        propagate_direct<<<NB, 64, 0, stream>>>(x, W, out);
    }
}

// Round 14
// 31.144 us; speedup vs baseline: 6.4333x; 6.4333x over previous
//
#include <hip/hip_runtime.h>
#include <hip/hip_bf16.h>

// RedistributionNetwork: 128 sequential tridiagonal layers on [256,1024] f32 state.
// Pipeline (2 kernels):
//  (A) gather_compose (byte-identical to round 8): one dwordx4 per (layer,row),
//      depth-4 compose -> bf16 band9[32][9][1024].
//  (B) propagate9y: 32 nine-diagonal steps, 1024 thr/block (16 waves = 4/SIMD,
//      double R11's TLP), 1 row/lane. Halo: 8 shuffles + windowed LDS edge
//      patches (compile-time register indices). Parity LDS double-buffer,
//      lgkmcnt-only barrier per step (weight prefetch stays in flight).

#define NXL 128
#define NYP 1024
#define NB  256
#define NQ  32     // quads
#define SL  128    // output rows per compose block
#define HR  136    // gathered rows per layer per block

struct __attribute__((packed, aligned(4))) f4u { float x, y, z, w; };

// ---------------- kernel A: fused gather + compose (identical to round 8) ----------------
__global__ __launch_bounds__(256) void gather_compose(const float* __restrict__ W,
                                                      __hip_bfloat16* __restrict__ band9) {
    __shared__ float ta[4][3][HR];
    const int blk = blockIdx.x;      // 0..255
    const int q   = blk >> 3;
    const int s   = blk & 7;
    const int i0  = s * SL;
    const int tid = threadIdx.x;

#pragma unroll
    for (int g = tid; g < 4 * HR; g += 256) {
        int ly = g / HR;
        int rr = g - ly * HR;
        int i  = i0 - 4 + rr;
        float a = 0.0f, b = 0.0f, c = 0.0f;
        if ((unsigned)i < NYP) {
            size_t base = ((size_t)(4 * q + ly) << 20) + (size_t)i * (NYP + 1);
            const float* lp = W + base + ((i == 0) ? 0 : (i == NYP - 1) ? -3 : -1);
            f4u v = *reinterpret_cast<const f4u*>(lp);
            if (i == 0)            { a = 0.0f; b = v.x; c = v.y; }
            else if (i == NYP - 1) { a = v.z;  b = v.w; c = 0.0f; }
            else                   { a = v.x;  b = v.y; c = v.z; }
        }
        ta[ly][0][rr] = a;
        ta[ly][1][rr] = b;
        ta[ly][2][rr] = c;
    }
    __syncthreads();

    if (tid < SL) {
        const int i  = i0 + tid;
        const int li = tid + 4;
        float p[11], r[11];
#pragma unroll
        for (int k = 0; k < 11; ++k) { p[k] = 0.0f; r[k] = 0.0f; }
        p[4] = ta[3][0][li]; p[5] = ta[3][1][li]; p[6] = ta[3][2][li];

#pragma unroll
        for (int d = -2; d <= 2; ++d)
            r[d + 5] = fmaf(p[d + 6], ta[2][0][li + d + 1],
                       fmaf(p[d + 5], ta[2][1][li + d],
                            p[d + 4] * ta[2][2][li + d - 1]));
#pragma unroll
        for (int k = 0; k < 11; ++k) p[k] = r[k];

#pragma unroll
        for (int d = -3; d <= 3; ++d)
            r[d + 5] = fmaf(p[d + 6], ta[1][0][li + d + 1],
                       fmaf(p[d + 5], ta[1][1][li + d],
                            p[d + 4] * ta[1][2][li + d - 1]));
#pragma unroll
        for (int k = 0; k < 11; ++k) p[k] = r[k];

#pragma unroll
        for (int d = -4; d <= 4; ++d)
            r[d + 5] = fmaf(p[d + 6], ta[0][0][li + d + 1],
                       fmaf(p[d + 5], ta[0][1][li + d],
                            p[d + 4] * ta[0][2][li + d - 1]));

        __hip_bfloat16* dst = band9 + (size_t)q * 9 * NYP + i;
#pragma unroll
        for (int d = 0; d < 9; ++d)
            dst[d * NYP] = __float2bfloat16(r[d + 1]);
    }
}

// ---------------- kernel B: 16-wave 9-diagonal propagation ----------------
__device__ __forceinline__ float bfu(unsigned short u) {
    return __uint_as_float(((unsigned)u) << 16);
}

__device__ __forceinline__ void ldsbar() {
    asm volatile("s_waitcnt lgkmcnt(0)" ::: "memory");
    __builtin_amdgcn_s_barrier();
}

__device__ __forceinline__ void loadWy(const __hip_bfloat16* __restrict__ band9,
                                       int q, int r, unsigned short (&u)[9]) {
    const unsigned short* base =
        reinterpret_cast<const unsigned short*>(band9 + (size_t)q * 9 * NYP + r);
#pragma unroll
    for (int d = 0; d < 9; ++d)
        u[d] = base[d * NYP];
}

// ebuf[par][B][8]: boundary B holds rows 64B-4 .. 64B+3.
// Edge lanes read a 4-float window CENTERED ON THEIR OWN ROW -> patch indices
// below are compile-time (no runtime register-array indexing).
__device__ __forceinline__ void read_win(const float (*e)[8], int w, int l,
                                         float (&wl)[4], float (&wr)[4]) {
    if (l < 4) {                      // rows r-4..r-1 = ebuf[w][l..l+3]
#pragma unroll
        for (int j = 0; j < 4; ++j) wl[j] = e[w][l + j];
    }
    if (l >= 60) {                    // rows r+1..r+4 = ebuf[w+1][l-59..l-56]
#pragma unroll
        for (int j = 0; j < 4; ++j) wr[j] = e[w + 1][l - 59 + j];
    }
}

__device__ __forceinline__ void stepY(float& h, const unsigned short (&q)[9],
                                      float (&wl)[4], float (&wr)[4],
                                      float (*nxt)[8], int w, int l) {
    float su1 = __shfl_up(h, 1),   su2 = __shfl_up(h, 2);
    float su3 = __shfl_up(h, 3),   su4 = __shfl_up(h, 4);
    float sd1 = __shfl_down(h, 1), sd2 = __shfl_down(h, 2);
    float sd3 = __shfl_down(h, 3), sd4 = __shfl_down(h, 4);
    // wave-edge patches; out-of-matrix rows killed by exact-0 band coefficients
    su1 = (l < 1) ? wl[3] : su1;
    su2 = (l < 2) ? wl[2] : su2;
    su3 = (l < 3) ? wl[1] : su3;
    su4 = (l < 4) ? wl[0] : su4;
    sd1 = (l > 62) ? wr[0] : sd1;
    sd2 = (l > 61) ? wr[1] : sd2;
    sd3 = (l > 60) ? wr[2] : sd3;
    sd4 = (l > 59) ? wr[3] : sd4;

    // two chains to halve dependent-FMA depth
    float a =           bfu(q[0]) * su4;
    a = fmaf(bfu(q[1]), su3, a);
    a = fmaf(bfu(q[2]), su2, a);
    a = fmaf(bfu(q[3]), su1, a);
    a = fmaf(bfu(q[4]), h,   a);
    float bb =          bfu(q[5]) * sd1;
    bb = fmaf(bfu(q[6]), sd2, bb);
    bb = fmaf(bfu(q[7]), sd3, bb);
    bb = fmaf(bfu(q[8]), sd4, bb);
    h = a + bb;

    // publish edge rows for next step into the other parity buffer
    if (l < 4)   nxt[w][4 + l]      = h;   // row 64w+l     -> boundary w, slot 4+l
    if (l >= 60) nxt[w + 1][l - 60] = h;   // row 64(w+1)-4+(l-60) -> boundary w+1
    ldsbar();                              // LDS-scope only; vmcnt stays in flight
    read_win(nxt, w, l, wl, wr);           // issue next step's window reads now
}

__global__ __launch_bounds__(1024) void propagate9y(const float* __restrict__ x,
                                                    const __hip_bfloat16* __restrict__ band9,
                                                    float* __restrict__ out) {
    __shared__ float ebuf[2][17][8];
    const int b = blockIdx.x;
    const int t = threadIdx.x;   // 0..1023 == row index
    const int w = t >> 6;
    const int l = t & 63;

    float h = x[(size_t)b * NYP + t];

    // zero the never-published corner slots (rows <0 and >=1024), both parities
    if (t < 4)                { ebuf[0][0][t] = 0.0f;  ebuf[1][0][t] = 0.0f; }
    else if (t >= 1020)       { ebuf[0][16][t - 1016] = 0.0f; ebuf[1][16][t - 1016] = 0.0f; }

    unsigned short qa[9], qb[9];
    loadWy(band9, 0, t, qa);

    // prologue: publish step-0 edge rows into parity 0
    if (l < 4)   ebuf[0][w][4 + l]      = h;
    if (l >= 60) ebuf[0][w + 1][l - 60] = h;
    ldsbar();
    float wl[4], wr[4];
    read_win(ebuf[0], w, l, wl, wr);

#pragma unroll 1
    for (int s = 0; s < NQ; s += 2) {
        loadWy(band9, (s + 1 < NQ) ? s + 1 : NQ - 1, t, qb);
        stepY(h, qa, wl, wr, ebuf[1], w, l);   // writes parity 1
        loadWy(band9, (s + 2 < NQ) ? s + 2 : NQ - 1, t, qa);
        stepY(h, qb, wl, wr, ebuf[0], w, l);   // writes parity 0
    }

    out[(size_t)b * NYP + t] = h;
}

// ---------------- fallback: direct tridiag sweep from W (ws too small) ----------------
__device__ __forceinline__ float gAw(const float* __restrict__ Wl, int r) {
    return (r >= 1 && r < NYP) ? Wl[(size_t)r * NYP + (r - 1)] : 0.0f;
}
__device__ __forceinline__ float gBw(const float* __restrict__ Wl, int r) {
    return ((unsigned)r < NYP) ? Wl[(size_t)r * NYP + r] : 0.0f;
}
__device__ __forceinline__ float gCw(const float* __restrict__ Wl, int r) {
    return (r >= 0 && r < NYP - 1) ? Wl[(size_t)r * NYP + (r + 1)] : 0.0f;
}

__global__ __launch_bounds__(64) void propagate_direct(const float* __restrict__ x,
                                                       const float* __restrict__ W,
                                                       float* __restrict__ out) {
    const int b    = blockIdx.x;
    const int lane = threadIdx.x & 63;
    const int r0   = lane * 16;

    float h[16];
    const float4* xb = reinterpret_cast<const float4*>(x + (size_t)b * NYP + r0);
#pragma unroll
    for (int t = 0; t < 4; ++t) {
        float4 v = xb[t];
        h[4 * t + 0] = v.x; h[4 * t + 1] = v.y;
        h[4 * t + 2] = v.z; h[4 * t + 3] = v.w;
    }

#pragma unroll 1
    for (int ll = 0; ll < NXL; ++ll) {
        const float* Wl = W + ((size_t)ll << 20);
        float a[16], bb[16], c[16];
#pragma unroll
        for (int k = 0; k < 16; ++k) {
            int i = r0 + k;
            a[k] = gAw(Wl, i); bb[k] = gBw(Wl, i); c[k] = gCw(Wl, i);
        }
        float left  = __shfl_up(h[15], 1);
        float right = __shfl_down(h[0], 1);
        float carry = left;
        float n[16];
#pragma unroll
        for (int j = 0; j < 16; ++j) {
            float hp = (j == 15) ? right : h[j + 1];
            n[j] = fmaf(a[j], carry, fmaf(bb[j], h[j], c[j] * hp));
            carry = h[j];
        }
#pragma unroll
        for (int j = 0; j < 16; ++j) h[j] = n[j];
    }

    float4* ob = reinterpret_cast<float4*>(out + (size_t)b * NYP + r0);
#pragma unroll
    for (int t = 0; t < 4; ++t)
        ob[t] = make_float4(h[4 * t + 0], h[4 * t + 1], h[4 * t + 2], h[4 * t + 3]);
}

extern "C" void kernel_launch(void* const* d_in, const int* in_sizes, int n_in,
                              void* d_out, int out_size, void* d_ws, size_t ws_size,
                              hipStream_t stream) {
    const float* x = (const float*)d_in[0];   // [256,1024] f32
    const float* W = (const float*)d_in[1];   // [128,1024,1024] f32
    float* out = (float*)d_out;               // [256,1024] f32

    const size_t band9Bytes = (size_t)NQ * 9 * NYP * sizeof(__hip_bfloat16);  // 576 KB
    if (ws_size >= band9Bytes) {
        __hip_bfloat16* band9 = (__hip_bfloat16*)d_ws;
        gather_compose<<<NQ * 8, 256, 0, stream>>>(W, band9);
        propagate9y<<<NB, 1024, 0, stream>>>(x, band9, out);
    } else {
        propagate_direct<<<NB, 64, 0, stream>>>(x, W, out);
    }
}